// Round 1
// baseline (642.002 us; speedup 1.0000x reference)
//
#include <hip/hip_runtime.h>
#include <hip/hip_bf16.h>
#include <stdint.h>

#define D_EMBED 1024
#define D_HID   4096
#define N_TOK   4096
#define N_EXP   8
#define CAP     4096

typedef __attribute__((ext_vector_type(4))) float f32x4;
typedef __attribute__((ext_vector_type(8))) short bf16x8;

__device__ __forceinline__ unsigned short f2bf(float f) {
    unsigned int u = __builtin_bit_cast(unsigned int, f);
    u += 0x7fffu + ((u >> 16) & 1u);          // round-to-nearest-even
    return (unsigned short)(u >> 16);
}

__device__ __forceinline__ void gload_lds16(const void* g, void* l) {
    __builtin_amdgcn_global_load_lds(
        (const __attribute__((address_space(1))) unsigned int*)g,
        (__attribute__((address_space(3))) unsigned int*)l,
        16, 0, 0);
}

// ---------------- x f32 -> bf16 ----------------
__global__ __launch_bounds__(256) void xcvt_kernel(const float* __restrict__ x,
                                                   unsigned short* __restrict__ xb, int n) {
    int i = (blockIdx.x * 256 + threadIdx.x) * 8;
    if (i >= n) return;
    f32x4 a = *reinterpret_cast<const f32x4*>(x + i);
    f32x4 b = *reinterpret_cast<const f32x4*>(x + i + 4);
    bf16x8 o;
    o[0]=(short)f2bf(a[0]); o[1]=(short)f2bf(a[1]); o[2]=(short)f2bf(a[2]); o[3]=(short)f2bf(a[3]);
    o[4]=(short)f2bf(b[0]); o[5]=(short)f2bf(b[1]); o[6]=(short)f2bf(b[2]); o[7]=(short)f2bf(b[3]);
    *reinterpret_cast<bf16x8*>(xb + i) = o;
}

// ------- pack W [E][R][C] f32 -> tiled bf16 [E][R/64][8 ksl][C][8 j] -------
// element (e,kb,ksl,col,j) = W[e][kb*64 + ksl*8 + j][col]
__global__ __launch_bounds__(256) void pack_w(const float* __restrict__ W,
                                              unsigned short* __restrict__ out, int R, int C) {
    int e = blockIdx.z, kb = blockIdx.y, cb = blockIdx.x;
    const float* Wp = W + (size_t)e * R * C + (size_t)(kb * 64) * C + cb * 64;
    unsigned short* op = out + (size_t)e * R * C;
    __shared__ unsigned short lds[64][72];
    int t = threadIdx.x;
    int r = t >> 2;
    int c0 = (t & 3) << 4;
    const float* src = Wp + (size_t)r * C + c0;
#pragma unroll
    for (int i = 0; i < 4; ++i) {
        f32x4 v = *reinterpret_cast<const f32x4*>(src + i * 4);
#pragma unroll
        for (int j = 0; j < 4; ++j) lds[r][c0 + i * 4 + j] = f2bf(v[j]);
    }
    __syncthreads();
#pragma unroll
    for (int i = 0; i < 2; ++i) {
        int cell = i * 256 + t;            // 0..511
        int ksl = cell >> 6, col = cell & 63;
        bf16x8 o;
#pragma unroll
        for (int j = 0; j < 8; ++j) o[j] = (short)lds[ksl * 8 + j][col];
        *reinterpret_cast<bf16x8*>(op + ((size_t)(kb * 8 + ksl) * C + cb * 64 + col) * 8) = o;
    }
}

// ---------------- gating: logits, top-2, softmax, scatter ----------------
__global__ __launch_bounds__(256) void gate_kernel(const float* __restrict__ x,
                                                   const float* __restrict__ Wg,
                                                   int* __restrict__ counts,
                                                   int* __restrict__ toks,
                                                   float* __restrict__ wgts) {
    int wave = threadIdx.x >> 6;
    int lane = threadIdx.x & 63;
    int tok = blockIdx.x * 4 + wave;
    const float* xp = x + (size_t)tok * D_EMBED;
    float acc[8] = {0, 0, 0, 0, 0, 0, 0, 0};
#pragma unroll
    for (int i = 0; i < 16; ++i) {
        int d = lane + 64 * i;
        float xv = xp[d];
        f32x4 w0 = *reinterpret_cast<const f32x4*>(Wg + (size_t)d * 8);
        f32x4 w1 = *reinterpret_cast<const f32x4*>(Wg + (size_t)d * 8 + 4);
        acc[0] += xv * w0[0]; acc[1] += xv * w0[1]; acc[2] += xv * w0[2]; acc[3] += xv * w0[3];
        acc[4] += xv * w1[0]; acc[5] += xv * w1[1]; acc[6] += xv * w1[2]; acc[7] += xv * w1[3];
    }
#pragma unroll
    for (int e = 0; e < 8; ++e)
        for (int s = 32; s; s >>= 1) acc[e] += __shfl_xor(acc[e], s, 64);
    if (lane == 0) {
        int i0 = 0; float v0 = acc[0];
#pragma unroll
        for (int e = 1; e < 8; ++e) if (acc[e] > v0) { v0 = acc[e]; i0 = e; }
        int i1 = -1; float v1 = -1e30f;
#pragma unroll
        for (int e = 0; e < 8; ++e) if (e != i0 && acc[e] > v1) { v1 = acc[e]; i1 = e; }
        float ex = __expf(v1 - v0);
        float w0 = 1.0f / (1.0f + ex);
        float w1 = 1.0f - w0;
        int p0 = atomicAdd(&counts[i0], 1);
        toks[i0 * CAP + p0] = tok; wgts[i0 * CAP + p0] = w0;
        int p1 = atomicAdd(&counts[i1], 1);
        toks[i1 * CAP + p1] = tok; wgts[i1 * CAP + p1] = w1;
    }
}

__global__ void prefix_kernel(const int* __restrict__ counts, int* __restrict__ offsets) {
    if (threadIdx.x == 0) {
        int s = 0;
        for (int e = 0; e < N_EXP; ++e) { offsets[e] = s; s += counts[e]; }
    }
}

// ---------------- GEMM1: h = silu(X@W1) * (X@W3), gathered rows ----------------
__global__ __launch_bounds__(256, 2) void gemm1_kernel(
    const unsigned short* __restrict__ xb,
    const unsigned short* __restrict__ wt1,
    const unsigned short* __restrict__ wt3,
    const int* __restrict__ counts, const int* __restrict__ offsets,
    const int* __restrict__ toks,
    unsigned short* __restrict__ h) {
    int e = blockIdx.z;
    int cnt = counts[e];
    int rowbase = blockIdx.y * 128;
    if (rowbase >= cnt) return;
    int colbase = blockIdx.x * 128;
    int off = offsets[e];

    __shared__ __align__(16) char Alds[16384];
    __shared__ __align__(16) char B1lds[16384];
    __shared__ __align__(16) char B3lds[16384];

    int t = threadIdx.x, lane = t & 63, wave = t >> 6;
    int wr = wave >> 1, wc = wave & 1;
    int q = lane >> 4, p = lane & 15;

    const unsigned short* wt1e = wt1 + (size_t)e * D_EMBED * D_HID;
    const unsigned short* wt3e = wt3 + (size_t)e * D_EMBED * D_HID;

    int r0 = rowbase + lane, r1 = rowbase + 64 + lane;
    int tok0 = (r0 < cnt) ? toks[e * CAP + r0] : 0;
    int tok1 = (r1 < cnt) ? toks[e * CAP + r1] : 0;
    const unsigned short* aSrc0 = xb + (size_t)tok0 * D_EMBED;
    const unsigned short* aSrc1 = xb + (size_t)tok1 * D_EMBED;

    f32x4 acc1[4][4] = {};
    f32x4 acc3[4][4] = {};
    int aBase = (q * 128 + wr * 64 + p) * 16;
    int bBase = (q * 128 + wc * 64 + p) * 16;

    for (int kt = 0; kt < 16; ++kt) {
        int kk = kt * 64;
        __syncthreads();
#pragma unroll
        for (int i = 0; i < 4; ++i) {
            int c = wave * 4 + i;           // 0..15
            int ksl = c >> 1;
            const unsigned short* asrc = ((c & 1) ? aSrc1 : aSrc0) + kk + ksl * 8;
            gload_lds16(asrc, Alds + c * 1024);
            size_t wofs = ((size_t)(kt * 8 + ksl) * D_HID + colbase + (c & 1) * 64 + lane) * 8;
            gload_lds16(wt1e + wofs, B1lds + c * 1024);
            gload_lds16(wt3e + wofs, B3lds + c * 1024);
        }
        __syncthreads();
#pragma unroll
        for (int ks = 0; ks < 2; ++ks) {
            bf16x8 af[4];
#pragma unroll
            for (int m = 0; m < 4; ++m)
                af[m] = *reinterpret_cast<const bf16x8*>(Alds + aBase + ks * 8192 + m * 256);
#pragma unroll
            for (int n = 0; n < 4; ++n) {
                bf16x8 b1 = *reinterpret_cast<const bf16x8*>(B1lds + bBase + ks * 8192 + n * 256);
                bf16x8 b3 = *reinterpret_cast<const bf16x8*>(B3lds + bBase + ks * 8192 + n * 256);
#pragma unroll
                for (int m = 0; m < 4; ++m) {
                    acc1[m][n] = __builtin_amdgcn_mfma_f32_16x16x32_bf16(af[m], b1, acc1[m][n], 0, 0, 0);
                    acc3[m][n] = __builtin_amdgcn_mfma_f32_16x16x32_bf16(af[m], b3, acc3[m][n], 0, 0, 0);
                }
            }
        }
    }
#pragma unroll
    for (int m = 0; m < 4; ++m) {
        int rl = wr * 64 + m * 16 + q * 4;
#pragma unroll
        for (int reg = 0; reg < 4; ++reg) {
            int grow = rowbase + rl + reg;
            if (grow >= cnt) continue;
            size_t hbase = (size_t)(off + grow) * D_HID + colbase + wc * 64;
#pragma unroll
            for (int n = 0; n < 4; ++n) {
                float a1 = acc1[m][n][reg], a3 = acc3[m][n][reg];
                float hv = (a1 / (1.0f + __expf(-a1))) * a3;
                h[hbase + n * 16 + p] = f2bf(hv);
            }
        }
    }
}

// ---------------- GEMM2: out[tok] += w * (h @ W2) ----------------
__global__ __launch_bounds__(256, 2) void gemm2_kernel(
    const unsigned short* __restrict__ h,
    const unsigned short* __restrict__ wt2,
    const int* __restrict__ counts, const int* __restrict__ offsets,
    const int* __restrict__ toks, const float* __restrict__ wgts,
    float* __restrict__ out) {
    int e = blockIdx.z;
    int cnt = counts[e];
    int rowbase = blockIdx.y * 128;
    if (rowbase >= cnt) return;
    int colbase = blockIdx.x * 128;
    int off = offsets[e];

    __shared__ __align__(16) char Alds[16384];
    __shared__ __align__(16) char Blds[16384];
    __shared__ float wLds[128];
    __shared__ int tokLds[128];

    int t = threadIdx.x, lane = t & 63, wave = t >> 6;
    int wr = wave >> 1, wc = wave & 1;
    int q = lane >> 4, p = lane & 15;

    if (t < 128) {
        int grow = rowbase + t;
        bool v = grow < cnt;
        wLds[t] = v ? wgts[e * CAP + grow] : 0.0f;
        tokLds[t] = v ? toks[e * CAP + grow] : 0;
    }

    const unsigned short* wt2e = wt2 + (size_t)e * D_HID * D_EMBED;
    int r0 = rowbase + lane, r1 = rowbase + 64 + lane;
    const unsigned short* aSrc0 = h + (size_t)(off + (r0 < cnt ? r0 : 0)) * D_HID;
    const unsigned short* aSrc1 = h + (size_t)(off + (r1 < cnt ? r1 : 0)) * D_HID;

    f32x4 acc[4][4] = {};
    int aBase = (q * 128 + wr * 64 + p) * 16;
    int bBase = (q * 128 + wc * 64 + p) * 16;

    for (int kt = 0; kt < 64; ++kt) {
        int kk = kt * 64;
        __syncthreads();
#pragma unroll
        for (int i = 0; i < 4; ++i) {
            int c = wave * 4 + i;
            int ksl = c >> 1;
            gload_lds16(((c & 1) ? aSrc1 : aSrc0) + kk + ksl * 8, Alds + c * 1024);
            gload_lds16(wt2e + ((size_t)(kt * 8 + ksl) * D_EMBED + colbase + (c & 1) * 64 + lane) * 8,
                        Blds + c * 1024);
        }
        __syncthreads();
#pragma unroll
        for (int ks = 0; ks < 2; ++ks) {
            bf16x8 af[4];
#pragma unroll
            for (int m = 0; m < 4; ++m)
                af[m] = *reinterpret_cast<const bf16x8*>(Alds + aBase + ks * 8192 + m * 256);
#pragma unroll
            for (int n = 0; n < 4; ++n) {
                bf16x8 bfr = *reinterpret_cast<const bf16x8*>(Blds + bBase + ks * 8192 + n * 256);
#pragma unroll
                for (int m = 0; m < 4; ++m)
                    acc[m][n] = __builtin_amdgcn_mfma_f32_16x16x32_bf16(af[m], bfr, acc[m][n], 0, 0, 0);
            }
        }
    }
#pragma unroll
    for (int m = 0; m < 4; ++m) {
#pragma unroll
        for (int reg = 0; reg < 4; ++reg) {
            int rl = wr * 64 + m * 16 + q * 4 + reg;
            float w = wLds[rl];
            int tok = tokLds[rl];
            float* obase = out + (size_t)tok * D_EMBED + colbase + wc * 64;
#pragma unroll
            for (int n = 0; n < 4; ++n)
                atomicAdd(obase + n * 16 + p, acc[m][n][reg] * w);
        }
    }
}

extern "C" void kernel_launch(void* const* d_in, const int* in_sizes, int n_in,
                              void* d_out, int out_size, void* d_ws, size_t ws_size,
                              hipStream_t stream) {
    const float* x  = (const float*)d_in[0];
    const float* Wg = (const float*)d_in[1];
    const float* W1 = (const float*)d_in[2];
    const float* W3 = (const float*)d_in[3];
    const float* W2 = (const float*)d_in[4];
    float* out = (float*)d_out;

    char* ws = (char*)d_ws;
    size_t szW = (size_t)N_EXP * D_EMBED * D_HID;       // elems per weight tensor
    unsigned short* wt1 = (unsigned short*)ws;  ws += szW * 2;
    unsigned short* wt3 = (unsigned short*)ws;  ws += szW * 2;
    unsigned short* wt2 = (unsigned short*)ws;  ws += szW * 2;
    unsigned short* hbuf = (unsigned short*)ws; ws += (size_t)2 * N_TOK * D_HID * 2;
    unsigned short* xb = (unsigned short*)ws;   ws += (size_t)N_TOK * D_EMBED * 2;
    int*   toks    = (int*)ws;   ws += (size_t)N_EXP * CAP * 4;
    float* wgts    = (float*)ws; ws += (size_t)N_EXP * CAP * 4;
    int*   counts  = (int*)ws;   ws += 8 * 4;
    int*   offsets = (int*)ws;   ws += 8 * 4;

    hipMemsetAsync(counts, 0, 8 * sizeof(int), stream);
    hipMemsetAsync(d_out, 0, (size_t)out_size * sizeof(float), stream);

    xcvt_kernel<<<(N_TOK * D_EMBED) / (256 * 8), 256, 0, stream>>>(x, xb, N_TOK * D_EMBED);
    pack_w<<<dim3(D_HID / 64, D_EMBED / 64, N_EXP), 256, 0, stream>>>(W1, wt1, D_EMBED, D_HID);
    pack_w<<<dim3(D_HID / 64, D_EMBED / 64, N_EXP), 256, 0, stream>>>(W3, wt3, D_EMBED, D_HID);
    pack_w<<<dim3(D_EMBED / 64, D_HID / 64, N_EXP), 256, 0, stream>>>(W2, wt2, D_HID, D_EMBED);
    gate_kernel<<<N_TOK / 4, 256, 0, stream>>>(x, Wg, counts, toks, wgts);
    prefix_kernel<<<1, 64, 0, stream>>>(counts, offsets);
    gemm1_kernel<<<dim3(D_HID / 128, 32, N_EXP), 256, 0, stream>>>(xb, wt1, wt3, counts, offsets, toks, hbuf);
    gemm2_kernel<<<dim3(D_EMBED / 128, 32, N_EXP), 256, 0, stream>>>(hbuf, wt2, counts, offsets, toks, wgts, out);
}